// Round 2
// baseline (7961.048 us; speedup 1.0000x reference)
//
#include <hip/hip_runtime.h>
#include <stdint.h>
#include <math.h>

typedef unsigned long long u64;
typedef unsigned int u32;

#define ATOT 242991   // total anchors per batch across 5 levels

__device__ __constant__ int    d_Wl[5]      = {304,152,76,38,19};
__device__ __constant__ int    d_stridec[5] = {4,8,16,32,64};
__device__ __constant__ double d_sized[5]   = {32.0,64.0,128.0,256.0,512.0};
__device__ __constant__ int    d_off[5]     = {0,182400,228000,239400,242250};
__device__ __constant__ int    d_Ncand[5]   = {182400,45600,11400,2850,741};

__device__ __forceinline__ u64 d2k(double d) {
  u64 b = (u64)__double_as_longlong(d);
  return (b & 0x8000000000000000ull) ? ~b : (b | 0x8000000000000000ull);
}

// ---------------- weight transpose: w[oc][ic][3][3] -> wt[ic][tap][oc] (f32) ----------
__global__ void wtrans_k(const float* __restrict__ w, float* __restrict__ wt) {
  int gid = blockIdx.x * 256 + threadIdx.x;           // over 2304*256
  if (gid >= 2304 * 256) return;
  int oc = gid & 255;
  int rest = gid >> 8;                                 // ic*9 + tap
  int ic = rest / 9, tap = rest % 9;
  wt[gid] = w[(oc * 256 + ic) * 9 + tap];
}

// ---------------- fused conv3x3+ReLU + 1x1 heads, FP64 accumulation ----------------
// block: 256 thr; tile 8x8 px, all 256 oc. thread: 4 px x 16 oc fp64 accumulators.
// LDS: weights as f64, padded layout [icr][ocg][tap][16] (stride 146 per ocg).
#define WLG 146
__global__ __launch_bounds__(256) void conv_head_k(
    const float* __restrict__ x, const float* __restrict__ wt,
    const float* __restrict__ convb, const float* __restrict__ clsw,
    const float* __restrict__ clsb, const float* __restrict__ regw,
    const float* __restrict__ regb, double* __restrict__ scr_all,
    double* __restrict__ reg_all, int H, int W, int lvl_off)
{
  __shared__ double wl[2 * 16 * WLG];   // 2 ic x 16 ocg x (9*16+2) = 4672 dbl = 36.5KB
  __shared__ double xl[2 * 120];        // 2 ic x 10 rows x (10+2 pad)

  const int t = threadIdx.x;
  const int ocg = t & 15, pxg = t >> 4;
  const int pr = pxg >> 1, pc0 = (pxg & 1) * 4;
  const int oc0 = ocg * 16;
  const int b = blockIdx.z;
  const int y0 = blockIdx.y * 8, x0 = blockIdx.x * 8;
  const int HW = H * W;
  const float* xb = x + (size_t)b * 256 * HW;

  double acc[4][16];
#pragma unroll
  for (int p = 0; p < 4; ++p)
#pragma unroll
    for (int o = 0; o < 16; ++o) acc[p][o] = 0.0;

  for (int ic0 = 0; ic0 < 256; ic0 += 2) {
    __syncthreads();
    // stage weights: 2 ic x 9 taps x 256 oc = 4608 f32 -> f64, padded layout
    {
      const float4* src = (const float4*)(wt + (size_t)ic0 * 2304);
      for (int q = t; q < 1152; q += 256) {
        float4 v = src[q];
        int q4 = q * 4;
        int icr = q4 / 2304, rem = q4 % 2304;
        int tap = rem >> 8, oc = rem & 255;
        double* dst = &wl[icr * (16 * WLG) + (oc >> 4) * WLG + tap * 16 + (oc & 15)];
        dst[0] = (double)v.x; dst[1] = (double)v.y;
        dst[2] = (double)v.z; dst[3] = (double)v.w;
      }
    }
    // stage input halo: 2 ic x 10 x 10 (row stride 12), f64
    if (t < 200) {
      int icr = t / 100, rr = (t / 10) % 10, cc = t % 10;
      int gy = y0 - 1 + rr, gx = x0 - 1 + cc;
      double v = 0.0;
      if ((unsigned)gy < (unsigned)H && (unsigned)gx < (unsigned)W)
        v = (double)xb[(size_t)(ic0 + icr) * HW + gy * W + gx];
      xl[icr * 120 + rr * 12 + cc] = v;
    }
    __syncthreads();
#pragma unroll
    for (int icr = 0; icr < 2; ++icr) {
#pragma unroll
      for (int ky = 0; ky < 3; ++ky) {
        const double* xrow = &xl[icr * 120 + (pr + ky) * 12 + pc0];
        double xd[6];
#pragma unroll
        for (int j = 0; j < 6; ++j) xd[j] = xrow[j];
#pragma unroll
        for (int kx = 0; kx < 3; ++kx) {
          const double* wp = &wl[icr * (16 * WLG) + ocg * WLG + (ky * 3 + kx) * 16];
          double wd[16];
#pragma unroll
          for (int o = 0; o < 16; ++o) wd[o] = wp[o];
#pragma unroll
          for (int p = 0; p < 4; ++p) {
            double xv = xd[p + kx];
#pragma unroll
            for (int o = 0; o < 16; ++o)
              acc[p][o] = fma(xv, wd[o], acc[p][o]);
          }
        }
      }
    }
  }
  // bias + relu in place (fp64)
#pragma unroll
  for (int p = 0; p < 4; ++p)
#pragma unroll
    for (int o = 0; o < 16; ++o)
      acc[p][o] = fmax(acc[p][o] + (double)convb[oc0 + o], 0.0);

  // heads: 15 dots per px; partial per lane over its 16 oc, butterfly over 16 lanes
  for (int head = 0; head < 15; ++head) {
    const float* hw = (head < 3) ? (clsw + head * 256) : (regw + (head - 3) * 256);
    double bias = (double)((head < 3) ? clsb[head] : regb[head - 3]);
    double hwd[16];
    {
      const float4* hp4 = (const float4*)(hw + oc0);
#pragma unroll
      for (int q = 0; q < 4; ++q) {
        float4 v = hp4[q];
        hwd[q * 4 + 0] = (double)v.x; hwd[q * 4 + 1] = (double)v.y;
        hwd[q * 4 + 2] = (double)v.z; hwd[q * 4 + 3] = (double)v.w;
      }
    }
#pragma unroll
    for (int p = 0; p < 4; ++p) {
      double part = 0.0;
#pragma unroll
      for (int o = 0; o < 16; ++o) part = fma(acc[p][o], hwd[o], part);
      part += __shfl_xor(part, 1);
      part += __shfl_xor(part, 2);
      part += __shfl_xor(part, 4);
      part += __shfl_xor(part, 8);
      if (ocg == 0) {
        int px = pxg * 4 + p;
        int gy = y0 + (px >> 3), gx = x0 + (px & 7);
        if (gy < H && gx < W) {
          double z = part + bias;
          int pix = gy * W + gx;
          size_t base = (size_t)b * ATOT + lvl_off + (size_t)pix * 3;
          if (head < 3) {
            scr_all[base + head] = 1.0 / (1.0 + exp(-z));
          } else {
            int hh = head - 3;
            reg_all[(base + (hh >> 2)) * 4 + (hh & 3)] = z;
          }
        }
      }
    }
  }
}

// ---------------- per-(batch,level) exact top-k via 2-pass radix select (u64 keys) ----
__device__ __forceinline__ void locate(int gid, int& b, int& r, int& lvl) {
  b = gid / ATOT; r = gid % ATOT;
  lvl = (r < 182400) ? 0 : (r < 228000) ? 1 : (r < 239400) ? 2 : (r < 242250) ? 3 : 4;
}

__global__ void hist_hi_k(const double* __restrict__ scr, u32* __restrict__ hist) {
  int gid = blockIdx.x * 256 + threadIdx.x;
  if (gid >= 2 * ATOT) return;
  int b, r, lvl; locate(gid, b, r, lvl);
  u64 kb = (u64)__double_as_longlong(scr[gid]);   // scores in (0,1): bits monotone
  atomicAdd(&hist[((b * 5 + lvl) << 16) + (u32)(kb >> 48)], 1u);
}

__global__ void scan_hi_k(const u32* __restrict__ hist, int* __restrict__ meta) {
  int bl = blockIdx.x, lvl = bl % 5;
  u32 k_sel = (u32)min(1000, d_Ncand[lvl]);
  const u32* h = hist + ((size_t)bl << 16);
  __shared__ u32 part[256];
  int t = threadIdx.x;
  u32 s = 0;
  for (int v = 0; v < 256; ++v) s += h[t * 256 + v];
  part[t] = s;
  __syncthreads();
  if (t == 0) {
    u32 cum = 0; int c = 255;
    for (; c > 0; --c) { if (cum + part[c] >= k_sel) break; cum += part[c]; }
    int pivot = c * 256;
    for (int v = c * 256 + 255; v >= c * 256; --v) {
      if (cum + h[v] >= k_sel) { pivot = v; break; }
      cum += h[v];
    }
    meta[bl * 8 + 0] = pivot;
    meta[bl * 8 + 1] = (int)cum;
  }
}

__global__ void hist_lo_k(const double* __restrict__ scr, const int* __restrict__ meta,
                          u32* __restrict__ hist) {
  int gid = blockIdx.x * 256 + threadIdx.x;
  if (gid >= 2 * ATOT) return;
  int b, r, lvl; locate(gid, b, r, lvl);
  int bl = b * 5 + lvl;
  u64 kb = (u64)__double_as_longlong(scr[gid]);
  if ((int)(kb >> 48) == meta[bl * 8 + 0])
    atomicAdd(&hist[(bl << 16) + (u32)((kb >> 32) & 0xFFFFu)], 1u);
}

__global__ void scan_lo_k(const u32* __restrict__ hist, int* __restrict__ meta) {
  int bl = blockIdx.x, lvl = bl % 5;
  u32 k_sel = (u32)min(1000, d_Ncand[lvl]);
  const u32* h = hist + ((size_t)bl << 16);
  __shared__ u32 part[256];
  int t = threadIdx.x;
  u32 s = 0;
  for (int v = 0; v < 256; ++v) s += h[t * 256 + v];
  part[t] = s;
  __syncthreads();
  if (t == 0) {
    u32 cum = (u32)meta[bl * 8 + 1];
    int c = 255;
    for (; c > 0; --c) { if (cum + part[c] >= k_sel) break; cum += part[c]; }
    int pivot = c * 256;
    for (int v = c * 256 + 255; v >= c * 256; --v) {
      if (cum + h[v] >= k_sel) { pivot = v; break; }
      cum += h[v];
    }
    // threshold on top-32 bits of the f64 key
    meta[bl * 8 + 2] = (int)((((u32)meta[bl * 8 + 0]) << 16) | (u32)pivot);
    meta[bl * 8 + 4] = 0;   // compact counter
  }
}

__global__ void compact_k(const double* __restrict__ scr, int* __restrict__ meta,
                          u64* __restrict__ comp) {
  int gid = blockIdx.x * 256 + threadIdx.x;
  if (gid >= 2 * ATOT) return;
  int b, r, lvl; locate(gid, b, r, lvl);
  int bl = b * 5 + lvl;
  u64 kb = (u64)__double_as_longlong(scr[gid]);
  if ((u32)(kb >> 32) >= (u32)meta[bl * 8 + 2]) {
    int pos = atomicAdd(&meta[bl * 8 + 4], 1);
    if (pos < 8192) {
      u32 li = (u32)(r - d_off[lvl]);          // < 2^18
      comp[((size_t)bl << 13) + pos] = ((kb >> 18) << 18) | (u64)(0x3FFFFu - li);
    }
  }
}

// descending bitonic sort of 8192 u64 in LDS, 1024 threads
__device__ void bitonic8192_desc(u64* s) {
  int t = threadIdx.x;
  for (int k = 2; k <= 8192; k <<= 1) {
    for (int j = k >> 1; j > 0; j >>= 1) {
      __syncthreads();
#pragma unroll
      for (int q = 0; q < 4; ++q) {
        int i = t + q * 1024;
        int l = (i << 1) - (i & (j - 1));
        int m = l + j;
        bool up = ((l & k) == 0);
        u64 a = s[l], bb = s[m];
        if ((a < bb) == up) { s[l] = bb; s[m] = a; }
      }
    }
  }
  __syncthreads();
}

__global__ __launch_bounds__(1024) void sort_level_k(const u64* __restrict__ comp,
                                                     const int* __restrict__ meta,
                                                     int* __restrict__ topidx) {
  int bl = blockIdx.x, lvl = bl % 5;
  int k_sel = min(1000, d_Ncand[lvl]);
  __shared__ u64 s[8192];
  int M = meta[bl * 8 + 4]; if (M > 8192) M = 8192;
  for (int i = threadIdx.x; i < 8192; i += 1024)
    s[i] = (i < M) ? comp[((size_t)bl << 13) + i] : 0ull;
  __syncthreads();
  bitonic8192_desc(s);
  for (int r = threadIdx.x; r < 1000; r += 1024) {
    int v = -1;
    if (r < k_sel && r < M) v = (int)(0x3FFFFu - (u32)(s[r] & 0x3FFFFu));
    topidx[bl * 1000 + r] = v;
  }
}

// ---------------- decode + clip + min-size (fp64) ----------------
__global__ void decode_k(const int* __restrict__ topidx, const double* __restrict__ scr_all,
                         const double* __restrict__ reg_all, double* __restrict__ boxes,
                         double* __restrict__ sc0) {
  int gid = blockIdx.x * 256 + threadIdx.x;
  if (gid >= 10000) return;
  int bl = gid / 1000, rank = gid % 1000;
  int b = bl / 5, lvl = bl % 5;
  int idx = topidx[bl * 1000 + rank];
  double X1 = 0.0, Y1 = 0.0, X2 = 0.0, Y2 = 0.0, sc = -1.0;
  if (idx >= 0) {
    size_t g = (size_t)b * ATOT + d_off[lvl] + idx;
    double s = scr_all[g];
    double dx = reg_all[g * 4 + 0], dy = reg_all[g * 4 + 1];
    const double BCLIP = 4.135166556742356;   // log(1000/16) in fp64
    double dw = fmin(reg_all[g * 4 + 2], BCLIP);
    double dh = fmin(reg_all[g * 4 + 3], BCLIP);
    int a = idx % 3, pix = idx / 3;
    int W = d_Wl[lvl];
    int py = pix / W, px = pix % W;
    double r = (a == 0) ? 2.0 : (a == 1) ? 1.0 : 0.5;
    double hr = sqrt(r);
    double size = d_sized[lvl];
    double wsz = size / hr, hsz = size * hr;
    double bx2 = rint(wsz * 0.5), by2 = rint(hsz * 0.5);
    double bx1 = rint(-(wsz * 0.5)), by1 = rint(-(hsz * 0.5));
    double sx = (double)(px * d_stridec[lvl]), sy = (double)(py * d_stridec[lvl]);
    double x1 = sx + bx1, yy1 = sy + by1;
    double x2 = sx + bx2, yy2 = sy + by2;
    double pw = x2 - x1, ph = yy2 - yy1;
    double pcx = x1 + 0.5 * pw, pcy = yy1 + 0.5 * ph;
    double cx = dx * pw + pcx, cy = dy * ph + pcy;
    double w = exp(dw) * pw, h = exp(dh) * ph;
    X1 = fmin(fmax(cx - 0.5 * w, 0.0), 1216.0);
    Y1 = fmin(fmax(cy - 0.5 * h, 0.0), 800.0);
    X2 = fmin(fmax(cx + 0.5 * w, 0.0), 1216.0);
    Y2 = fmin(fmax(cy + 0.5 * h, 0.0), 800.0);
    sc = ((X2 - X1) > 0.001 && (Y2 - Y1) > 0.001) ? s : -1.0;
  }
  double* bp = boxes + (size_t)(bl * 1000 + rank) * 4;
  bp[0] = X1; bp[1] = Y1; bp[2] = X2; bp[3] = Y2;
  sc0[bl * 1000 + rank] = sc;
}

// ---------------- greedy NMS (fp64 IoU): bitmasks + sequential 64-lane scan ----------
__global__ __launch_bounds__(256) void nms_k(const double* __restrict__ boxes,
                                             double* __restrict__ sc0,
                                             u64* __restrict__ gmask) {
  int bl = blockIdx.x;
  __shared__ double X1[1000], Y1[1000], X2[1000], Y2[1000], AR[1000], SS[1000];
  int t = threadIdx.x;
  for (int i = t; i < 1000; i += 256) {
    const double* bp = boxes + (size_t)(bl * 1000 + i) * 4;
    double x1 = bp[0], y1 = bp[1], x2 = bp[2], y2 = bp[3];
    X1[i] = x1; Y1[i] = y1; X2[i] = x2; Y2[i] = y2;
    AR[i] = (x2 - x1) * (y2 - y1);
    SS[i] = sc0[bl * 1000 + i];
  }
  __syncthreads();
  u64* gm = gmask + (size_t)bl * 16000;
  for (int i = t; i < 1000; i += 256) {
    double ax1 = X1[i], ay1 = Y1[i], ax2 = X2[i], ay2 = Y2[i], aa = AR[i];
    for (int wj = 0; wj < 16; ++wj) {
      u64 bits = 0;
      int jbase = wj * 64;
      for (int jb = 0; jb < 64; ++jb) {
        int j = jbase + jb;
        if (j <= i || j >= 1000) continue;
        double lx = fmax(ax1, X1[j]), ly = fmax(ay1, Y1[j]);
        double rx = fmin(ax2, X2[j]), ry = fmin(ay2, Y2[j]);
        double ww = fmax(rx - lx, 0.0), hh = fmax(ry - ly, 0.0);
        double inter = ww * hh;
        double uni = (aa + AR[j]) - inter;
        double iou = inter / fmax(uni, 1e-9);
        if (iou > 0.7) bits |= (1ull << jb);
      }
      gm[i * 16 + wj] = bits;
    }
  }
  __syncthreads();
  if (t < 64) {
    int lane = t;
    u64 keepw = 0;
    if (lane < 16) {
      for (int jb = 0; jb < 64; ++jb) {
        int j = lane * 64 + jb;
        if (j < 1000 && SS[j] > -0.5) keepw |= (1ull << jb);
      }
    }
    u64 m0 = 0, m1 = 0, m2 = 0, m3 = 0;
    if (lane < 16) {
      m0 = gm[0 * 16 + lane]; m1 = gm[1 * 16 + lane];
      m2 = gm[2 * 16 + lane]; m3 = gm[3 * 16 + lane];
    }
    for (int i = 0; i < 1000; i += 4) {
      u64 n0 = 0, n1 = 0, n2 = 0, n3 = 0;
      if (lane < 16 && i + 4 < 1000) {
        n0 = gm[(i + 4) * 16 + lane]; n1 = gm[(i + 5) * 16 + lane];
        n2 = gm[(i + 6) * 16 + lane]; n3 = gm[(i + 7) * 16 + lane];
      }
      { u64 kw = __shfl(keepw, (i    ) >> 6); if ((kw >> ((i    ) & 63)) & 1) { if (lane < 16) keepw &= ~m0; } }
      { u64 kw = __shfl(keepw, (i + 1) >> 6); if ((kw >> ((i + 1) & 63)) & 1) { if (lane < 16) keepw &= ~m1; } }
      { u64 kw = __shfl(keepw, (i + 2) >> 6); if ((kw >> ((i + 2) & 63)) & 1) { if (lane < 16) keepw &= ~m2; } }
      { u64 kw = __shfl(keepw, (i + 3) >> 6); if ((kw >> ((i + 3) & 63)) & 1) { if (lane < 16) keepw &= ~m3; } }
      m0 = n0; m1 = n1; m2 = n2; m3 = n3;
    }
    if (lane < 16) {
      for (int jb = 0; jb < 64; ++jb) {
        int j = lane * 64 + jb;
        if (j < 1000) sc0[bl * 1000 + j] = ((keepw >> jb) & 1) ? SS[j] : -1.0;
      }
    }
  }
}

// ---------------- image-level top-1000 of 5000 + output assembly ----------------
__global__ __launch_bounds__(1024) void final_k(const double* __restrict__ sc0,
                                                const double* __restrict__ boxes,
                                                float* __restrict__ out) {
  int b = blockIdx.x;
  __shared__ u64 s[8192];
  for (int i = threadIdx.x; i < 8192; i += 1024) {
    u64 v = 0;
    if (i < 5000) {
      u64 k = d2k(sc0[b * 5000 + i]);
      v = ((k >> 18) << 18) | (u64)(0x3FFFFu - (u32)i);
    }
    s[i] = v;
  }
  __syncthreads();
  bitonic8192_desc(s);
  for (int r = threadIdx.x; r < 1000; r += 1024) {
    u64 v = s[r];
    int idx = (int)(0x3FFFFu - (u32)(v & 0x3FFFFu));
    double score = sc0[b * 5000 + idx];
    const double* bp = boxes + (size_t)(b * 5000 + idx) * 4;
    float* op = out + ((size_t)b * 1000 + r) * 5;
    op[0] = (float)bp[0]; op[1] = (float)bp[1];
    op[2] = (float)bp[2]; op[3] = (float)bp[3];
    op[4] = (float)score;
  }
}

// ---------------- host ----------------
extern "C" void kernel_launch(void* const* d_in, const int* in_sizes, int n_in,
                              void* d_out, int out_size, void* d_ws, size_t ws_size,
                              hipStream_t stream) {
  const float* p[5];
  for (int i = 0; i < 5; ++i) p[i] = (const float*)d_in[i];
  const float* conv_w = (const float*)d_in[5];
  const float* conv_b = (const float*)d_in[6];
  const float* cls_w  = (const float*)d_in[7];
  const float* cls_b  = (const float*)d_in[8];
  const float* reg_w  = (const float*)d_in[9];
  const float* reg_b  = (const float*)d_in[10];
  float* out = (float*)d_out;

  char* ws = (char*)d_ws;
  size_t off = 0;
  auto alloc = [&](size_t bytes) -> void* {
    void* pt = ws + off;
    off = (off + bytes + 255) & ~(size_t)255;
    return pt;
  };
  float*  wt      = (float*) alloc(2304ull * 256 * 4);      // 2.36 MB
  double* scr_all = (double*)alloc(2ull * ATOT * 8);        // 3.89 MB
  double* reg_all = (double*)alloc(2ull * ATOT * 4 * 8);    // 15.55 MB
  u32*    hist    = (u32*)   alloc(10ull * 65536 * 4);      // 2.62 MB
  int*    meta    = (int*)   alloc(10ull * 8 * 4);
  u64*    comp    = (u64*)   alloc(10ull * 8192 * 8);       // 0.66 MB
  int*    topidx  = (int*)   alloc(10ull * 1000 * 4);
  double* boxes   = (double*)alloc(2ull * 5000 * 4 * 8);    // 0.32 MB
  double* sc0     = (double*)alloc(2ull * 5000 * 8);
  u64*    gmask   = (u64*)   alloc(10ull * 1000 * 16 * 8);  // 1.28 MB

  wtrans_k<<<(2304 * 256 + 255) / 256, 256, 0, stream>>>(conv_w, wt);

  const int Hs[5] = {200, 100, 50, 25, 13};
  const int Ws[5] = {304, 152, 76, 38, 19};
  const int offs[5] = {0, 182400, 228000, 239400, 242250};
  for (int l = 0; l < 5; ++l) {
    dim3 g((Ws[l] + 7) / 8, (Hs[l] + 7) / 8, 2);
    conv_head_k<<<g, 256, 0, stream>>>(p[l], wt, conv_b, cls_w, cls_b, reg_w, reg_b,
                                       scr_all, reg_all, Hs[l], Ws[l], offs[l]);
  }

  int nblk = (2 * ATOT + 255) / 256;
  hipMemsetAsync(hist, 0, 10ull * 65536 * 4, stream);
  hist_hi_k<<<nblk, 256, 0, stream>>>(scr_all, hist);
  scan_hi_k<<<10, 256, 0, stream>>>(hist, meta);
  hipMemsetAsync(hist, 0, 10ull * 65536 * 4, stream);
  hist_lo_k<<<nblk, 256, 0, stream>>>(scr_all, meta, hist);
  scan_lo_k<<<10, 256, 0, stream>>>(hist, meta);
  compact_k<<<nblk, 256, 0, stream>>>(scr_all, meta, comp);
  sort_level_k<<<10, 1024, 0, stream>>>(comp, meta, topidx);
  decode_k<<<40, 256, 0, stream>>>(topidx, scr_all, reg_all, boxes, sc0);
  nms_k<<<10, 256, 0, stream>>>(boxes, sc0, gmask);
  final_k<<<2, 1024, 0, stream>>>(sc0, boxes, out);
}

// Round 3
// 3997.790 us; speedup vs baseline: 1.9914x; 1.9914x over previous
//
#include <hip/hip_runtime.h>
#include <stdint.h>
#include <math.h>

typedef unsigned long long u64;
typedef unsigned int u32;
typedef unsigned char u8;

#define ATOT 242991    // total anchors per batch
#define PXTOT 80997    // total pixels per batch

__device__ __constant__ int    d_Hs[5]      = {200,100,50,25,13};
__device__ __constant__ int    d_Ws[5]      = {304,152,76,38,19};
__device__ __constant__ int    d_stridec[5] = {4,8,16,32,64};
__device__ __constant__ double d_sized[5]   = {32.0,64.0,128.0,256.0,512.0};
__device__ __constant__ int    d_off[5]     = {0,182400,228000,239400,242250};
__device__ __constant__ int    d_pxoff[6]   = {0,60800,76000,79800,80750,80997};
__device__ __constant__ int    d_Ncand[5]   = {182400,45600,11400,2850,741};
__device__ __constant__ int    d_tbase[6]   = {0,1900,2394,2534,2574,2586};
__device__ __constant__ int    d_TW[5]      = {38,19,10,5,3};

__device__ __forceinline__ u32 f2k32(float f) {
  u32 u = __float_as_uint(f);
  return (u & 0x80000000u) ? ~u : (u | 0x80000000u);
}
__device__ __forceinline__ float k2f32(u32 k) {
  u32 u = (k & 0x80000000u) ? (k & 0x7FFFFFFFu) : ~k;
  return __uint_as_float(u);
}
__device__ __forceinline__ u64 d2k(double d) {
  u64 b = (u64)__double_as_longlong(d);
  return (b & 0x8000000000000000ull) ? ~b : (b | 0x8000000000000000ull);
}

// ---------------- weight transpose: w[oc][ic][3][3] -> wt[ic][tap][oc] (f32) ----------
__global__ void wtrans_k(const float* __restrict__ w, float* __restrict__ wt) {
  int gid = blockIdx.x * 256 + threadIdx.x;
  if (gid >= 2304 * 256) return;
  int oc = gid & 255;
  int rest = gid >> 8;
  int ic = rest / 9, tap = rest % 9;
  wt[gid] = w[(oc * 256 + ic) * 9 + tap];
}

// ---------------- PHASE A: fp32 conv3x3+ReLU + cls head, ALL levels, one launch -------
// block: 256 thr; tile 8x8 px x 256 oc; thread: 4 px x 16 oc fp32 acc.
#define WLG 148    // padded oc-group stride (floats): ocg*148 mod 32 -> 2-way max (free)
__global__ __launch_bounds__(256, 4) void conv_head32_k(
    const float* __restrict__ x0, const float* __restrict__ x1,
    const float* __restrict__ x2, const float* __restrict__ x3,
    const float* __restrict__ x4,
    const float* __restrict__ wt, const float* __restrict__ convb,
    const float* __restrict__ clsw, const float* __restrict__ clsb,
    float* __restrict__ scr32)
{
  __shared__ float wl[4 * 16 * WLG];   // 4 ic x [ocg][tap][16] = 37,888 B
  __shared__ float xl[4 * 120];        // 4 ic x 10 rows x 12

  const int bid = blockIdx.x;
  int lvl = 0;
#pragma unroll
  for (int l = 1; l < 5; ++l) if (bid >= d_tbase[l]) lvl = l;
  const int lid = bid - d_tbase[lvl];
  const int H = d_Hs[lvl], W = d_Ws[lvl];
  const int TW = d_TW[lvl];
  const int tiles = TW * ((H + 7) / 8);
  const int b = lid / tiles;
  const int t2 = lid % tiles;
  const int y0 = (t2 / TW) * 8, x0c = (t2 % TW) * 8;

  const float* xs[5] = {x0, x1, x2, x3, x4};
  const int HW = H * W;
  const float* xb = xs[lvl] + (size_t)b * 256 * HW;

  const int t = threadIdx.x;
  const int ocg = t & 15, pxg = t >> 4;
  const int pr = pxg >> 1, pc0 = (pxg & 1) * 4;
  const int oc0 = ocg * 16;

  float acc[4][16];
#pragma unroll
  for (int p = 0; p < 4; ++p)
#pragma unroll
    for (int o = 0; o < 16; ++o) acc[p][o] = 0.f;

  for (int ic0 = 0; ic0 < 256; ic0 += 4) {
    __syncthreads();
    // stage weights: 4 ic x 9 tap x 256 oc -> padded layout
    {
      const float4* src = (const float4*)(wt + (size_t)ic0 * 2304);
#pragma unroll
      for (int i = 0; i < 9; ++i) {
        int q = t + i * 256;                 // < 2304
        float4 v = src[q];
        int q4 = q * 4;
        int icr = q4 / 2304, rem = q4 % 2304;
        int tap = rem >> 8, oc = rem & 255;
        float* dst = &wl[icr * (16 * WLG) + (oc >> 4) * WLG + tap * 16 + (oc & 15)];
        *(float4*)dst = v;
      }
    }
    // stage input halo: 4 ic x 10 x 10 (row stride 12)
    for (int q = t; q < 400; q += 256) {
      int icr = q / 100, rr = (q / 10) % 10, cc = q % 10;
      int gy = y0 - 1 + rr, gx = x0c - 1 + cc;
      float v = 0.f;
      if ((unsigned)gy < (unsigned)H && (unsigned)gx < (unsigned)W)
        v = xb[(size_t)(ic0 + icr) * HW + gy * W + gx];
      xl[icr * 120 + rr * 12 + cc] = v;
    }
    __syncthreads();
#pragma unroll
    for (int icr = 0; icr < 4; ++icr) {
#pragma unroll
      for (int ky = 0; ky < 3; ++ky) {
        const float* xrow = &xl[icr * 120 + (pr + ky) * 12 + pc0];
        float4 xa = *(const float4*)xrow;
        float4 xc = *(const float4*)(xrow + 4);
        float xr[8] = {xa.x, xa.y, xa.z, xa.w, xc.x, xc.y, xc.z, xc.w};
#pragma unroll
        for (int kx = 0; kx < 3; ++kx) {
          const float* wp = &wl[icr * (16 * WLG) + ocg * WLG + (ky * 3 + kx) * 16];
          float wv[16];
#pragma unroll
          for (int q = 0; q < 4; ++q) {
            float4 wq = ((const float4*)wp)[q];
            wv[q * 4 + 0] = wq.x; wv[q * 4 + 1] = wq.y;
            wv[q * 4 + 2] = wq.z; wv[q * 4 + 3] = wq.w;
          }
#pragma unroll
          for (int p = 0; p < 4; ++p) {
            float xv = xr[p + kx];
#pragma unroll
            for (int o = 0; o < 16; ++o)
              acc[p][o] = fmaf(xv, wv[o], acc[p][o]);
          }
        }
      }
    }
  }
  // bias + relu
#pragma unroll
  for (int p = 0; p < 4; ++p)
#pragma unroll
    for (int o = 0; o < 16; ++o)
      acc[p][o] = fmaxf(acc[p][o] + convb[oc0 + o], 0.f);

  // cls heads only (3), fp32, 16-lane butterfly
  const int lvl_off = d_off[lvl];
#pragma unroll
  for (int head = 0; head < 3; ++head) {
    const float* hw = clsw + head * 256;
    float hwv[16];
    {
      const float4* hp4 = (const float4*)(hw + oc0);
#pragma unroll
      for (int q = 0; q < 4; ++q) {
        float4 v = hp4[q];
        hwv[q * 4 + 0] = v.x; hwv[q * 4 + 1] = v.y;
        hwv[q * 4 + 2] = v.z; hwv[q * 4 + 3] = v.w;
      }
    }
#pragma unroll
    for (int p = 0; p < 4; ++p) {
      float part = 0.f;
#pragma unroll
      for (int o = 0; o < 16; ++o) part = fmaf(acc[p][o], hwv[o], part);
      part += __shfl_xor(part, 1);
      part += __shfl_xor(part, 2);
      part += __shfl_xor(part, 4);
      part += __shfl_xor(part, 8);
      if (ocg == 0) {
        int px = pxg * 4 + p;
        int gy = y0 + (px >> 3), gx = x0c + (px & 7);
        if (gy < H && gx < W) {
          float z = part + clsb[head];
          int pix = gy * W + gx;
          scr32[(size_t)b * ATOT + lvl_off + (size_t)pix * 3 + head] =
              1.f / (1.f + expf(-z));
        }
      }
    }
  }
}

// ---------------- PHASE B: fp32 radix select with safety margin ----------------
__device__ __forceinline__ void locate(int gid, int& b, int& r, int& lvl) {
  b = gid / ATOT; r = gid % ATOT;
  lvl = (r < 182400) ? 0 : (r < 228000) ? 1 : (r < 239400) ? 2 : (r < 242250) ? 3 : 4;
}

__global__ void hist_hi_k(const float* __restrict__ scr, u32* __restrict__ hist) {
  int gid = blockIdx.x * 256 + threadIdx.x;
  if (gid >= 2 * ATOT) return;
  int b, r, lvl; locate(gid, b, r, lvl);
  u32 key = f2k32(scr[gid]);
  atomicAdd(&hist[((b * 5 + lvl) << 16) + (key >> 16)], 1u);
}

__global__ void scan_hi_k(const u32* __restrict__ hist, int* __restrict__ meta) {
  int bl = blockIdx.x, lvl = bl % 5;
  u32 k_sel = (u32)min(1000, d_Ncand[lvl]);
  const u32* h = hist + ((size_t)bl << 16);
  __shared__ u32 part[256];
  int t = threadIdx.x;
  u32 s = 0;
  for (int v = 0; v < 256; ++v) s += h[t * 256 + v];
  part[t] = s;
  __syncthreads();
  if (t == 0) {
    u32 cum = 0; int c = 255;
    for (; c > 0; --c) { if (cum + part[c] >= k_sel) break; cum += part[c]; }
    int pivot = c * 256;
    for (int v = c * 256 + 255; v >= c * 256; --v) {
      if (cum + h[v] >= k_sel) { pivot = v; break; }
      cum += h[v];
    }
    meta[bl * 8 + 0] = pivot;
    meta[bl * 8 + 1] = (int)cum;
  }
}

__global__ void hist_lo_k(const float* __restrict__ scr, const int* __restrict__ meta,
                          u32* __restrict__ hist) {
  int gid = blockIdx.x * 256 + threadIdx.x;
  if (gid >= 2 * ATOT) return;
  int b, r, lvl; locate(gid, b, r, lvl);
  int bl = b * 5 + lvl;
  u32 key = f2k32(scr[gid]);
  if ((int)(key >> 16) == meta[bl * 8 + 0])
    atomicAdd(&hist[(bl << 16) + (key & 0xFFFFu)], 1u);
}

__global__ void scan_lo_k(const u32* __restrict__ hist, int* __restrict__ meta) {
  int bl = blockIdx.x, lvl = bl % 5;
  u32 k_sel = (u32)min(1000, d_Ncand[lvl]);
  const u32* h = hist + ((size_t)bl << 16);
  __shared__ u32 part[256];
  int t = threadIdx.x;
  u32 s = 0;
  for (int v = 0; v < 256; ++v) s += h[t * 256 + v];
  part[t] = s;
  __syncthreads();
  if (t == 0) {
    u32 cum = (u32)meta[bl * 8 + 1];
    int c = 255;
    for (; c > 0; --c) { if (cum + part[c] >= k_sel) break; cum += part[c]; }
    int pivot = c * 256;
    for (int v = c * 256 + 255; v >= c * 256; --v) {
      if (cum + h[v] >= k_sel) { pivot = v; break; }
      cum += h[v];
    }
    u32 P = (((u32)meta[bl * 8 + 0]) << 16) | (u32)pivot;   // exact fp32 kth key
    u32 T = f2k32(k2f32(P) - 1e-3f);                        // safety margin
    if (d_Ncand[lvl] <= 1000) T = 0;                        // keep all
    meta[bl * 8 + 2] = (int)T;
    meta[bl * 8 + 4] = 0;   // compact counter
  }
}

__global__ void compact_k(const float* __restrict__ scr, int* __restrict__ meta,
                          u32* __restrict__ complist, u8* __restrict__ flags) {
  int gid = blockIdx.x * 256 + threadIdx.x;
  if (gid >= 2 * ATOT) return;
  int b, r, lvl; locate(gid, b, r, lvl);
  int bl = b * 5 + lvl;
  u32 key = f2k32(scr[gid]);
  if (key >= (u32)meta[bl * 8 + 2]) {
    int pos = atomicAdd(&meta[bl * 8 + 4], 1);
    if (pos < 8192) {
      u32 li = (u32)(r - d_off[lvl]);
      complist[bl * 8192 + pos] = li;
      flags[b * PXTOT + d_pxoff[lvl] + li / 3] = 1;
    }
  }
}

__global__ void pxcompact_k(u8* __restrict__ flags, u32* __restrict__ worklist,
                            int* __restrict__ wlcount) {
  int gid = blockIdx.x * 256 + threadIdx.x;
  if (gid >= 2 * PXTOT) return;
  if (flags[gid]) {
    flags[gid] = 0;                       // self-clean for next replay
    int pos = atomicAdd(wlcount, 1);
    if (pos < 65536) worklist[pos] = (u32)gid;
  }
}

// ---------------- PHASE C: sparse fp64 rescore of flagged pixels ----------------
#define RSG 2048
__global__ __launch_bounds__(256) void rescore_k(
    const float* __restrict__ x0, const float* __restrict__ x1,
    const float* __restrict__ x2, const float* __restrict__ x3,
    const float* __restrict__ x4,
    const float* __restrict__ wt, const float* __restrict__ convb,
    const float* __restrict__ clsw, const float* __restrict__ clsb,
    const float* __restrict__ regw, const float* __restrict__ regb,
    const u32* __restrict__ worklist, const int* __restrict__ wlcount,
    double* __restrict__ scr64, double* __restrict__ reg64)
{
  __shared__ float xl[4 * 3072];     // 48KB: [slot][ic][12]
  __shared__ double hl[4 * 256];     // 8KB
  const float* xs[5] = {x0, x1, x2, x3, x4};
  const int t = threadIdx.x;
  int count = *wlcount; if (count > 65536) count = 65536;

  for (int base = blockIdx.x * 4; base < count; base += RSG * 4) {
    int sb[4], slvl[4], spix[4];
    bool valid[4];
#pragma unroll
    for (int s = 0; s < 4; ++s) {
      int w = base + s;
      valid[s] = (w < count);
      sb[s] = 0; slvl[s] = 0; spix[s] = 0;
      if (valid[s]) {
        u32 g = worklist[w];
        int b = (int)(g / PXTOT), lp = (int)(g % PXTOT);
        int lvl = 0;
#pragma unroll
        for (int l = 1; l < 5; ++l) if (lp >= d_pxoff[l]) lvl = l;
        sb[s] = b; slvl[s] = lvl; spix[s] = lp - d_pxoff[lvl];
      }
    }
    __syncthreads();
    // stage halos: thread t = ic t, 9 taps per slot
#pragma unroll
    for (int s = 0; s < 4; ++s) {
      if (valid[s]) {
        int lvl = slvl[s], H = d_Hs[lvl], W = d_Ws[lvl];
        int py = spix[s] / W, px = spix[s] % W;
        const float* xb = xs[lvl] + ((size_t)sb[s] * 256 + t) * H * W;
#pragma unroll
        for (int ky = 0; ky < 3; ++ky) {
          int gy = py - 1 + ky;
#pragma unroll
          for (int kx = 0; kx < 3; ++kx) {
            int gx = px - 1 + kx;
            float v = 0.f;
            if ((unsigned)gy < (unsigned)H && (unsigned)gx < (unsigned)W)
              v = xb[gy * W + gx];
            xl[s * 3072 + t * 12 + ky * 3 + kx] = v;
          }
        }
      }
    }
    __syncthreads();
    double h[4] = {0.0, 0.0, 0.0, 0.0};
    for (int ic = 0; ic < 256; ++ic) {
      double wd[9];
#pragma unroll
      for (int tap = 0; tap < 9; ++tap)
        wd[tap] = (double)wt[(ic * 9 + tap) * 256 + t];
#pragma unroll
      for (int s = 0; s < 4; ++s) {
        const float* xp = &xl[s * 3072 + ic * 12];
        float4 a = *(const float4*)xp;
        float4 bq = *(const float4*)(xp + 4);
        float c = xp[8];
        h[s] = fma((double)a.x, wd[0], h[s]);
        h[s] = fma((double)a.y, wd[1], h[s]);
        h[s] = fma((double)a.z, wd[2], h[s]);
        h[s] = fma((double)a.w, wd[3], h[s]);
        h[s] = fma((double)bq.x, wd[4], h[s]);
        h[s] = fma((double)bq.y, wd[5], h[s]);
        h[s] = fma((double)bq.z, wd[6], h[s]);
        h[s] = fma((double)bq.w, wd[7], h[s]);
        h[s] = fma((double)c,    wd[8], h[s]);
      }
    }
    double bias = (double)convb[t];
#pragma unroll
    for (int s = 0; s < 4; ++s) {
      h[s] = fmax(h[s] + bias, 0.0);
      hl[s * 256 + t] = h[s];
    }
    __syncthreads();
    // heads: wave w handles slot w; 64-lane partial + butterfly
    {
      int s = t >> 6, lane = t & 63;
      if (valid[s]) {
        int lvl = slvl[s];
        size_t g3 = (size_t)sb[s] * ATOT + d_off[lvl] + (size_t)spix[s] * 3;
        for (int head = 0; head < 15; ++head) {
          const float* hw = (head < 3) ? (clsw + head * 256) : (regw + (head - 3) * 256);
          double part = 0.0;
#pragma unroll
          for (int q = 0; q < 4; ++q) {
            int oc = lane + q * 64;
            part = fma(hl[s * 256 + oc], (double)hw[oc], part);
          }
          part += __shfl_xor(part, 32);
          part += __shfl_xor(part, 16);
          part += __shfl_xor(part, 8);
          part += __shfl_xor(part, 4);
          part += __shfl_xor(part, 2);
          part += __shfl_xor(part, 1);
          if (lane == 0) {
            double z = part + (double)((head < 3) ? clsb[head] : regb[head - 3]);
            if (head < 3) scr64[g3 + head] = 1.0 / (1.0 + exp(-z));
            else { int hh = head - 3; reg64[(g3 + (hh >> 2)) * 4 + (hh & 3)] = z; }
          }
        }
      }
    }
    __syncthreads();
  }
}

// ---------------- PHASE D: exact fp64 keys, sort, decode, NMS, final ----------------
__global__ void buildkeys_k(const u32* __restrict__ complist, const int* __restrict__ meta,
                            const double* __restrict__ scr64, u64* __restrict__ comp64) {
  int bl = blockIdx.x;
  int b = bl / 5, lvl = bl % 5;
  int M = meta[bl * 8 + 4]; if (M > 8192) M = 8192;
  for (int i = threadIdx.x; i < 8192; i += 256) {
    u64 key = 0;
    if (i < M) {
      u32 li = complist[bl * 8192 + i];
      double sc = scr64[(size_t)b * ATOT + d_off[lvl] + li];
      key = ((d2k(sc) >> 18) << 18) | (u64)(0x3FFFFu - li);
    }
    comp64[bl * 8192 + i] = key;
  }
}

__device__ void bitonic8192_desc(u64* s) {
  int t = threadIdx.x;
  for (int k = 2; k <= 8192; k <<= 1) {
    for (int j = k >> 1; j > 0; j >>= 1) {
      __syncthreads();
#pragma unroll
      for (int q = 0; q < 4; ++q) {
        int i = t + q * 1024;
        int l = (i << 1) - (i & (j - 1));
        int m = l + j;
        bool up = ((l & k) == 0);
        u64 a = s[l], bb = s[m];
        if ((a < bb) == up) { s[l] = bb; s[m] = a; }
      }
    }
  }
  __syncthreads();
}

__global__ __launch_bounds__(1024) void sort_level_k(const u64* __restrict__ comp64,
                                                     const int* __restrict__ meta,
                                                     int* __restrict__ topidx) {
  int bl = blockIdx.x, lvl = bl % 5;
  int k_sel = min(1000, d_Ncand[lvl]);
  __shared__ u64 s[8192];
  int M = meta[bl * 8 + 4]; if (M > 8192) M = 8192;
  for (int i = threadIdx.x; i < 8192; i += 1024)
    s[i] = (i < M) ? comp64[bl * 8192 + i] : 0ull;
  __syncthreads();
  bitonic8192_desc(s);
  for (int r = threadIdx.x; r < 1000; r += 1024) {
    int v = -1;
    if (r < k_sel && r < M) v = (int)(0x3FFFFu - (u32)(s[r] & 0x3FFFFu));
    topidx[bl * 1000 + r] = v;
  }
}

__global__ void decode_k(const int* __restrict__ topidx, const double* __restrict__ scr64,
                         const double* __restrict__ reg64, double* __restrict__ boxes,
                         double* __restrict__ sc0) {
  int gid = blockIdx.x * 256 + threadIdx.x;
  if (gid >= 10000) return;
  int bl = gid / 1000, rank = gid % 1000;
  int b = bl / 5, lvl = bl % 5;
  int idx = topidx[bl * 1000 + rank];
  double X1 = 0.0, Y1 = 0.0, X2 = 0.0, Y2 = 0.0, sc = -1.0;
  if (idx >= 0) {
    size_t g = (size_t)b * ATOT + d_off[lvl] + idx;
    double s = scr64[g];
    double dx = reg64[g * 4 + 0], dy = reg64[g * 4 + 1];
    const double BCLIP = 4.135166556742356;
    double dw = fmin(reg64[g * 4 + 2], BCLIP);
    double dh = fmin(reg64[g * 4 + 3], BCLIP);
    int a = idx % 3, pix = idx / 3;
    int W = d_Ws[lvl];
    int py = pix / W, px = pix % W;
    double r = (a == 0) ? 2.0 : (a == 1) ? 1.0 : 0.5;
    double hr = sqrt(r);
    double size = d_sized[lvl];
    double wsz = size / hr, hsz = size * hr;
    double bx2 = rint(wsz * 0.5), by2 = rint(hsz * 0.5);
    double bx1 = rint(-(wsz * 0.5)), by1 = rint(-(hsz * 0.5));
    double sx = (double)(px * d_stridec[lvl]), sy = (double)(py * d_stridec[lvl]);
    double x1 = sx + bx1, yy1 = sy + by1;
    double x2 = sx + bx2, yy2 = sy + by2;
    double pw = x2 - x1, ph = yy2 - yy1;
    double pcx = x1 + 0.5 * pw, pcy = yy1 + 0.5 * ph;
    double cx = dx * pw + pcx, cy = dy * ph + pcy;
    double w = exp(dw) * pw, h = exp(dh) * ph;
    X1 = fmin(fmax(cx - 0.5 * w, 0.0), 1216.0);
    Y1 = fmin(fmax(cy - 0.5 * h, 0.0), 800.0);
    X2 = fmin(fmax(cx + 0.5 * w, 0.0), 1216.0);
    Y2 = fmin(fmax(cy + 0.5 * h, 0.0), 800.0);
    sc = ((X2 - X1) > 0.001 && (Y2 - Y1) > 0.001) ? s : -1.0;
  }
  double* bp = boxes + (size_t)(bl * 1000 + rank) * 4;
  bp[0] = X1; bp[1] = Y1; bp[2] = X2; bp[3] = Y2;
  sc0[bl * 1000 + rank] = sc;
}

// NMS mask build: 40 blocks (bl x quarter), fp64 IoU
__global__ __launch_bounds__(256) void nms_mask_k(const double* __restrict__ boxes,
                                                  u64* __restrict__ gmask) {
  int blk = blockIdx.x;
  int bl = blk >> 2, qt = blk & 3;
  __shared__ double X1[1000], Y1[1000], X2[1000], Y2[1000], AR[1000];
  int t = threadIdx.x;
  for (int i = t; i < 1000; i += 256) {
    const double* bp = boxes + (size_t)(bl * 1000 + i) * 4;
    double x1 = bp[0], y1 = bp[1], x2 = bp[2], y2 = bp[3];
    X1[i] = x1; Y1[i] = y1; X2[i] = x2; Y2[i] = y2;
    AR[i] = (x2 - x1) * (y2 - y1);
  }
  __syncthreads();
  if (t < 250) {
    int i = qt * 250 + t;
    double ax1 = X1[i], ay1 = Y1[i], ax2 = X2[i], ay2 = Y2[i], aa = AR[i];
    u64* gm = gmask + (size_t)bl * 16000 + (size_t)i * 16;
    for (int wj = 0; wj < 16; ++wj) {
      u64 bits = 0;
      int jb0 = wj * 64;
      for (int jb = 0; jb < 64; ++jb) {
        int j = jb0 + jb;
        if (j <= i || j >= 1000) continue;
        double lx = fmax(ax1, X1[j]), ly = fmax(ay1, Y1[j]);
        double rx = fmin(ax2, X2[j]), ry = fmin(ay2, Y2[j]);
        double ww = fmax(rx - lx, 0.0), hh = fmax(ry - ly, 0.0);
        double inter = ww * hh;
        double uni = (aa + AR[j]) - inter;
        double iou = inter / fmax(uni, 1e-9);
        if (iou > 0.7) bits |= (1ull << jb);
      }
      gm[wj] = bits;
    }
  }
}

// NMS sequential scan: 10 blocks x 64 lanes
__global__ void nms_scan_k(double* __restrict__ sc0, const u64* __restrict__ gmask) {
  int bl = blockIdx.x;
  int lane = threadIdx.x;
  const u64* gm = gmask + (size_t)bl * 16000;
  u64 keepw = 0;
  if (lane < 16) {
    for (int jb = 0; jb < 64; ++jb) {
      int j = lane * 64 + jb;
      if (j < 1000 && sc0[bl * 1000 + j] > -0.5) keepw |= (1ull << jb);
    }
  }
  u64 m0 = 0, m1 = 0, m2 = 0, m3 = 0;
  if (lane < 16) {
    m0 = gm[0 * 16 + lane]; m1 = gm[1 * 16 + lane];
    m2 = gm[2 * 16 + lane]; m3 = gm[3 * 16 + lane];
  }
  for (int i = 0; i < 1000; i += 4) {
    u64 n0 = 0, n1 = 0, n2 = 0, n3 = 0;
    if (lane < 16 && i + 4 < 1000) {
      n0 = gm[(i + 4) * 16 + lane]; n1 = gm[(i + 5) * 16 + lane];
      n2 = gm[(i + 6) * 16 + lane]; n3 = gm[(i + 7) * 16 + lane];
    }
    { u64 kw = __shfl(keepw, (i    ) >> 6); if ((kw >> ((i    ) & 63)) & 1) { if (lane < 16) keepw &= ~m0; } }
    { u64 kw = __shfl(keepw, (i + 1) >> 6); if ((kw >> ((i + 1) & 63)) & 1) { if (lane < 16) keepw &= ~m1; } }
    { u64 kw = __shfl(keepw, (i + 2) >> 6); if ((kw >> ((i + 2) & 63)) & 1) { if (lane < 16) keepw &= ~m2; } }
    { u64 kw = __shfl(keepw, (i + 3) >> 6); if ((kw >> ((i + 3) & 63)) & 1) { if (lane < 16) keepw &= ~m3; } }
    m0 = n0; m1 = n1; m2 = n2; m3 = n3;
  }
  if (lane < 16) {
    for (int jb = 0; jb < 64; ++jb) {
      int j = lane * 64 + jb;
      if (j < 1000) {
        double ss = sc0[bl * 1000 + j];
        sc0[bl * 1000 + j] = ((keepw >> jb) & 1) ? ss : -1.0;
      }
    }
  }
}

__global__ __launch_bounds__(1024) void final_k(const double* __restrict__ sc0,
                                                const double* __restrict__ boxes,
                                                float* __restrict__ out) {
  int b = blockIdx.x;
  __shared__ u64 s[8192];
  for (int i = threadIdx.x; i < 8192; i += 1024) {
    u64 v = 0;
    if (i < 5000) {
      u64 k = d2k(sc0[b * 5000 + i]);
      v = ((k >> 18) << 18) | (u64)(0x3FFFFu - (u32)i);
    }
    s[i] = v;
  }
  __syncthreads();
  bitonic8192_desc(s);
  for (int r = threadIdx.x; r < 1000; r += 1024) {
    u64 v = s[r];
    int idx = (int)(0x3FFFFu - (u32)(v & 0x3FFFFu));
    double score = sc0[b * 5000 + idx];
    const double* bp = boxes + (size_t)(b * 5000 + idx) * 4;
    float* op = out + ((size_t)b * 1000 + r) * 5;
    op[0] = (float)bp[0]; op[1] = (float)bp[1];
    op[2] = (float)bp[2]; op[3] = (float)bp[3];
    op[4] = (float)score;
  }
}

// ---------------- host ----------------
extern "C" void kernel_launch(void* const* d_in, const int* in_sizes, int n_in,
                              void* d_out, int out_size, void* d_ws, size_t ws_size,
                              hipStream_t stream) {
  const float* p[5];
  for (int i = 0; i < 5; ++i) p[i] = (const float*)d_in[i];
  const float* conv_w = (const float*)d_in[5];
  const float* conv_b = (const float*)d_in[6];
  const float* cls_w  = (const float*)d_in[7];
  const float* cls_b  = (const float*)d_in[8];
  const float* reg_w  = (const float*)d_in[9];
  const float* reg_b  = (const float*)d_in[10];
  float* out = (float*)d_out;

  char* ws = (char*)d_ws;
  size_t off = 0;
  auto alloc = [&](size_t bytes) -> void* {
    void* pt = ws + off;
    off = (off + bytes + 255) & ~(size_t)255;
    return pt;
  };
  float*  wt       = (float*) alloc(2304ull * 256 * 4);     // 2.36 MB
  float*  scr32    = (float*) alloc(2ull * ATOT * 4);       // 1.94 MB
  double* scr64    = (double*)alloc(2ull * ATOT * 8);       // 3.89 MB
  double* reg64    = (double*)alloc(2ull * ATOT * 4 * 8);   // 15.55 MB
  u32*    hist     = (u32*)   alloc(10ull * 65536 * 4);     // 2.62 MB
  int*    meta     = (int*)   alloc(10ull * 8 * 4);
  u32*    complist = (u32*)   alloc(10ull * 8192 * 4);      // 0.33 MB
  u64*    comp64   = (u64*)   alloc(10ull * 8192 * 8);      // 0.66 MB
  u8*     flags    = (u8*)    alloc(2ull * PXTOT);          // 0.16 MB
  u32*    worklist = (u32*)   alloc(65536ull * 4);          // 0.26 MB
  int*    wlcount  = (int*)   alloc(256);
  int*    topidx   = (int*)   alloc(10ull * 1000 * 4);
  double* boxes    = (double*)alloc(2ull * 5000 * 4 * 8);   // 0.32 MB
  double* sc0      = (double*)alloc(2ull * 5000 * 8);
  u64*    gmask    = (u64*)   alloc(10ull * 1000 * 16 * 8); // 1.28 MB

  wtrans_k<<<(2304 * 256 + 255) / 256, 256, 0, stream>>>(conv_w, wt);

  conv_head32_k<<<2586, 256, 0, stream>>>(p[0], p[1], p[2], p[3], p[4],
                                          wt, conv_b, cls_w, cls_b, scr32);

  int nblk = (2 * ATOT + 255) / 256;
  hipMemsetAsync(hist, 0, 10ull * 65536 * 4, stream);
  hist_hi_k<<<nblk, 256, 0, stream>>>(scr32, hist);
  scan_hi_k<<<10, 256, 0, stream>>>(hist, meta);
  hipMemsetAsync(hist, 0, 10ull * 65536 * 4, stream);
  hist_lo_k<<<nblk, 256, 0, stream>>>(scr32, meta, hist);
  scan_lo_k<<<10, 256, 0, stream>>>(hist, meta);

  hipMemsetAsync(flags, 0, 2ull * PXTOT, stream);
  hipMemsetAsync(wlcount, 0, 4, stream);
  compact_k<<<nblk, 256, 0, stream>>>(scr32, meta, complist, flags);
  pxcompact_k<<<(2 * PXTOT + 255) / 256, 256, 0, stream>>>(flags, worklist, wlcount);

  rescore_k<<<RSG, 256, 0, stream>>>(p[0], p[1], p[2], p[3], p[4],
                                     wt, conv_b, cls_w, cls_b, reg_w, reg_b,
                                     worklist, wlcount, scr64, reg64);

  buildkeys_k<<<10, 256, 0, stream>>>(complist, meta, scr64, comp64);
  sort_level_k<<<10, 1024, 0, stream>>>(comp64, meta, topidx);
  decode_k<<<40, 256, 0, stream>>>(topidx, scr64, reg64, boxes, sc0);
  nms_mask_k<<<40, 256, 0, stream>>>(boxes, gmask);
  nms_scan_k<<<10, 64, 0, stream>>>(sc0, gmask);
  final_k<<<2, 1024, 0, stream>>>(sc0, boxes, out);
}